// Round 1
// baseline (1734.898 us; speedup 1.0000x reference)
//
#include <hip/hip_runtime.h>

// Problem constants (fixed by reference setup_inputs)
#define N_USERS 100000
#define N_ITEMS 50000
#define NN      (N_USERS + N_ITEMS)   // 150000 nodes
#define DD      64                     // feature dim
#define E_EDGES 2400000
#define HOPS    3

// ---------------------------------------------------------------------------
// init: ego = concat(user_emb, item_emb); next = 0; acc(d_out) = 0
// Operates on float4 granularity. N*D/4 = 2.4M float4 elements.
// ---------------------------------------------------------------------------
__global__ void init_kernel(const float4* __restrict__ user4,
                            const float4* __restrict__ item4,
                            float4* __restrict__ ego4,
                            float4* __restrict__ next4,
                            float4* __restrict__ acc4) {
    const int n4 = NN * DD / 4;
    const int u4 = N_USERS * DD / 4;
    int i = blockIdx.x * blockDim.x + threadIdx.x;
    if (i >= n4) return;
    float4 v = (i < u4) ? user4[i] : item4[i - u4];
    ego4[i]  = v;
    next4[i] = make_float4(0.f, 0.f, 0.f, 0.f);
    acc4[i]  = make_float4(0.f, 0.f, 0.f, 0.f);
}

// ---------------------------------------------------------------------------
// scatter SpMM: one wave per edge; lane d handles feature column d.
// y[rows[e]*64 + d] += vals[e] * x[cols[e]*64 + d]
// blockDim = 256 -> 4 edges per block.
// ---------------------------------------------------------------------------
__global__ void spmm_scatter(const int*   __restrict__ rows,
                             const int*   __restrict__ cols,
                             const float* __restrict__ vals,
                             const float* __restrict__ x,
                             float*       __restrict__ y) {
    int e = blockIdx.x * 4 + (threadIdx.x >> 6);
    if (e >= E_EDGES) return;
    int lane = threadIdx.x & 63;
    int r = rows[e];
    int c = cols[e];
    float v = vals[e];
    atomicAdd(&y[r * DD + lane], v * x[c * DD + lane]);
}

// ---------------------------------------------------------------------------
// acc += src * scale; and zero the other ping-pong buffer for the next hop.
// ---------------------------------------------------------------------------
__global__ void axpy_zero(const float4* __restrict__ src4,
                          float4* __restrict__ acc4,
                          float4* __restrict__ zero4,
                          float scale) {
    const int n4 = NN * DD / 4;
    int i = blockIdx.x * blockDim.x + threadIdx.x;
    if (i >= n4) return;
    float4 s = src4[i];
    float4 a = acc4[i];
    a.x += s.x * scale;
    a.y += s.y * scale;
    a.z += s.z * scale;
    a.w += s.w * scale;
    acc4[i]  = a;
    zero4[i] = make_float4(0.f, 0.f, 0.f, 0.f);
}

extern "C" void kernel_launch(void* const* d_in, const int* in_sizes, int n_in,
                              void* d_out, int out_size, void* d_ws, size_t ws_size,
                              hipStream_t stream) {
    const float* user_emb = (const float*)d_in[0];
    const float* item_emb = (const float*)d_in[1];
    const int*   adj_rows = (const int*)d_in[2];
    const int*   adj_cols = (const int*)d_in[3];
    const float* adj_vals = (const float*)d_in[4];
    // d_in[5] = hops (scalar, always 3 per setup_inputs) -- unrolled host-side.

    float* acc  = (float*)d_out;               // NN*DD floats, node order = output order
    float* buf0 = (float*)d_ws;                // ego ping
    float* buf1 = buf0 + (size_t)NN * DD;      // ego pong

    const int n4 = NN * DD / 4;
    const int tpb = 256;
    const int grid_n4 = (n4 + tpb - 1) / tpb;
    const int grid_e  = (E_EDGES + 3) / 4;     // 4 edges per 256-thread block
    const float scale = 1.0f / (float)HOPS;

    // ego(buf0) <- inputs; buf1 <- 0; acc <- 0
    init_kernel<<<grid_n4, tpb, 0, stream>>>(
        (const float4*)user_emb, (const float4*)item_emb,
        (float4*)buf0, (float4*)buf1, (float4*)acc);

    // hop 1: buf0 -> buf1 ; acc += buf1/3 ; zero buf0
    spmm_scatter<<<grid_e, tpb, 0, stream>>>(adj_rows, adj_cols, adj_vals, buf0, buf1);
    axpy_zero<<<grid_n4, tpb, 0, stream>>>((const float4*)buf1, (float4*)acc, (float4*)buf0, scale);

    // hop 2: buf1 -> buf0 ; acc += buf0/3 ; zero buf1
    spmm_scatter<<<grid_e, tpb, 0, stream>>>(adj_rows, adj_cols, adj_vals, buf1, buf0);
    axpy_zero<<<grid_n4, tpb, 0, stream>>>((const float4*)buf0, (float4*)acc, (float4*)buf1, scale);

    // hop 3: buf0 -> buf1 ; acc += buf1/3 ; zero buf0 (uniform work every call)
    spmm_scatter<<<grid_e, tpb, 0, stream>>>(adj_rows, adj_cols, adj_vals, buf0, buf1);
    axpy_zero<<<grid_n4, tpb, 0, stream>>>((const float4*)buf1, (float4*)acc, (float4*)buf0, scale);
}

// Round 2
// 812.291 us; speedup vs baseline: 2.1358x; 2.1358x over previous
//
#include <hip/hip_runtime.h>

// Problem constants (fixed by reference setup_inputs)
#define N_USERS 100000
#define N_ITEMS 50000
#define NN      (N_USERS + N_ITEMS)   // 150000 nodes
#define DD      64                     // feature dim
#define E_EDGES 2400000
#define HOPS    3
#define SCAN_B  256
#define NB      ((NN + SCAN_B - 1) / SCAN_B)   // 586 scan blocks

// ---------------------------------------------------------------------------
// init: ego = concat(user_emb, item_emb); acc(d_out) = 0
// ---------------------------------------------------------------------------
__global__ void init_kernel(const float4* __restrict__ user4,
                            const float4* __restrict__ item4,
                            float4* __restrict__ ego4,
                            float4* __restrict__ acc4) {
    const int n4 = NN * DD / 4;
    const int u4 = N_USERS * DD / 4;
    int i = blockIdx.x * blockDim.x + threadIdx.x;
    if (i >= n4) return;
    float4 v = (i < u4) ? user4[i] : item4[i - u4];
    ego4[i] = v;
    acc4[i] = make_float4(0.f, 0.f, 0.f, 0.f);
}

// ---------------------------------------------------------------------------
// CSR build step 1: degree histogram into row_ptr[0..NN-1] (pre-zeroed)
// ---------------------------------------------------------------------------
__global__ void hist_kernel(const int* __restrict__ rows, int* __restrict__ deg) {
    int e = blockIdx.x * blockDim.x + threadIdx.x;
    if (e < E_EDGES) atomicAdd(&deg[rows[e]], 1);
}

// ---------------------------------------------------------------------------
// CSR build step 2a: per-block exclusive scan (in-place) + block sums
// ---------------------------------------------------------------------------
__global__ void scan_local(int* __restrict__ data, int* __restrict__ bsum, int n) {
    __shared__ int sh[SCAN_B];
    int i = blockIdx.x * SCAN_B + threadIdx.x;
    int v = (i < n) ? data[i] : 0;
    sh[threadIdx.x] = v;
    __syncthreads();
    for (int off = 1; off < SCAN_B; off <<= 1) {
        int t = (threadIdx.x >= off) ? sh[threadIdx.x - off] : 0;
        __syncthreads();
        sh[threadIdx.x] += t;
        __syncthreads();
    }
    int incl = sh[threadIdx.x];
    if (i < n) data[i] = incl - v;                     // exclusive
    if (threadIdx.x == SCAN_B - 1) bsum[blockIdx.x] = incl;
}

// ---------------------------------------------------------------------------
// CSR build step 2b: single-block exclusive scan of block sums (NB <= 1024)
// ---------------------------------------------------------------------------
__global__ void scan_bsum(int* __restrict__ bsum, int nb) {
    __shared__ int sh[1024];
    int v = ((int)threadIdx.x < nb) ? bsum[threadIdx.x] : 0;
    sh[threadIdx.x] = v;
    __syncthreads();
    for (int off = 1; off < 1024; off <<= 1) {
        int t = ((int)threadIdx.x >= off) ? sh[threadIdx.x - off] : 0;
        __syncthreads();
        sh[threadIdx.x] += t;
        __syncthreads();
    }
    if ((int)threadIdx.x < nb) bsum[threadIdx.x] = sh[threadIdx.x] - v;
}

// ---------------------------------------------------------------------------
// CSR build step 2c: add block offsets; init cursor = row_ptr; set sentinel
// (launched with SCAN_B threads/block so blockIdx.x == scan chunk id)
// ---------------------------------------------------------------------------
__global__ void add_offsets(int* __restrict__ row_ptr, int* __restrict__ cursor,
                            const int* __restrict__ bsum) {
    int i = blockIdx.x * SCAN_B + threadIdx.x;
    if (i < NN) {
        int v = row_ptr[i] + bsum[blockIdx.x];
        row_ptr[i] = v;
        cursor[i]  = v;
    }
    if (i == 0) row_ptr[NN] = E_EDGES;
}

// ---------------------------------------------------------------------------
// CSR build step 3: scatter (col,val) into row-sorted arrays
// ---------------------------------------------------------------------------
__global__ void scatter_edges(const int* __restrict__ rows,
                              const int* __restrict__ cols,
                              const float* __restrict__ vals,
                              int* __restrict__ cursor,
                              int* __restrict__ scols,
                              float* __restrict__ svals) {
    int e = blockIdx.x * blockDim.x + threadIdx.x;
    if (e >= E_EDGES) return;
    int r = rows[e];
    int pos = atomicAdd(&cursor[r], 1);
    scols[pos] = cols[e];
    svals[pos] = vals[e];
}

// ---------------------------------------------------------------------------
// CSR SpMM, atomic-free: one wave per row, lane = feature column.
// Fused epilogue: y[r] = sum; acc[r] += sum * scale.
// blockDim = 256 -> 4 rows per block.
// ---------------------------------------------------------------------------
__global__ void spmm_csr(const int* __restrict__ row_ptr,
                         const int* __restrict__ scols,
                         const float* __restrict__ svals,
                         const float* __restrict__ x,
                         float* __restrict__ y,
                         float* __restrict__ acc,
                         float scale) {
    int r = blockIdx.x * 4 + (threadIdx.x >> 6);
    if (r >= NN) return;
    int lane = threadIdx.x & 63;
    int s    = row_ptr[r];
    int eend = row_ptr[r + 1];
    float sum = 0.f;
    int e = s;
    for (; e + 1 < eend; e += 2) {          // unroll x2 for load pipelining
        int   c0 = scols[e],     c1 = scols[e + 1];
        float v0 = svals[e],     v1 = svals[e + 1];
        sum += v0 * x[c0 * DD + lane];
        sum += v1 * x[c1 * DD + lane];
    }
    if (e < eend)
        sum += svals[e] * x[scols[e] * DD + lane];
    int o = r * DD + lane;
    y[o] = sum;
    acc[o] += sum * scale;
}

// ---------------------------------------------------------------------------
// Fallback path (round-1 kernels) if workspace is too small for CSR build.
// ---------------------------------------------------------------------------
__global__ void init_fb(const float4* __restrict__ user4,
                        const float4* __restrict__ item4,
                        float4* __restrict__ ego4,
                        float4* __restrict__ next4,
                        float4* __restrict__ acc4) {
    const int n4 = NN * DD / 4;
    const int u4 = N_USERS * DD / 4;
    int i = blockIdx.x * blockDim.x + threadIdx.x;
    if (i >= n4) return;
    float4 v = (i < u4) ? user4[i] : item4[i - u4];
    ego4[i]  = v;
    next4[i] = make_float4(0.f, 0.f, 0.f, 0.f);
    acc4[i]  = make_float4(0.f, 0.f, 0.f, 0.f);
}

__global__ void spmm_scatter(const int* __restrict__ rows,
                             const int* __restrict__ cols,
                             const float* __restrict__ vals,
                             const float* __restrict__ x,
                             float* __restrict__ y) {
    int e = blockIdx.x * 4 + (threadIdx.x >> 6);
    if (e >= E_EDGES) return;
    int lane = threadIdx.x & 63;
    atomicAdd(&y[rows[e] * DD + lane], vals[e] * x[cols[e] * DD + lane]);
}

__global__ void axpy_zero(const float4* __restrict__ src4,
                          float4* __restrict__ acc4,
                          float4* __restrict__ zero4,
                          float scale) {
    const int n4 = NN * DD / 4;
    int i = blockIdx.x * blockDim.x + threadIdx.x;
    if (i >= n4) return;
    float4 s = src4[i];
    float4 a = acc4[i];
    a.x += s.x * scale; a.y += s.y * scale;
    a.z += s.z * scale; a.w += s.w * scale;
    acc4[i]  = a;
    zero4[i] = make_float4(0.f, 0.f, 0.f, 0.f);
}

extern "C" void kernel_launch(void* const* d_in, const int* in_sizes, int n_in,
                              void* d_out, int out_size, void* d_ws, size_t ws_size,
                              hipStream_t stream) {
    const float* user_emb = (const float*)d_in[0];
    const float* item_emb = (const float*)d_in[1];
    const int*   adj_rows = (const int*)d_in[2];
    const int*   adj_cols = (const int*)d_in[3];
    const float* adj_vals = (const float*)d_in[4];
    // d_in[5] = hops (always 3 per setup_inputs) -- unrolled host-side.

    float* acc = (float*)d_out;

    const int tpb = 256;
    const int n4 = NN * DD / 4;
    const int grid_n4 = (n4 + tpb - 1) / tpb;          // 9375
    const int grid_e  = (E_EDGES + tpb - 1) / tpb;     // 9375
    const int grid_r  = (NN + 3) / 4;                  // 37500 (4 rows/block)
    const float scale = 1.0f / (float)HOPS;

    // Workspace layout (CSR path): 97.2 MB total
    float* buf0    = (float*)d_ws;                      // NN*DD
    float* buf1    = buf0 + (size_t)NN * DD;            // NN*DD
    int*   row_ptr = (int*)(buf1 + (size_t)NN * DD);    // NN+1
    int*   cursor  = row_ptr + NN + 1;                  // NN
    int*   bsum    = cursor + NN;                       // 1024 (pad)
    int*   scols   = bsum + 1024;                       // E
    float* svals   = (float*)(scols + E_EDGES);         // E
    const size_t needed = ((size_t)2 * NN * DD + (2 * NN + 1 + 1024)
                           + (size_t)2 * E_EDGES) * 4;

    if (ws_size >= needed) {
        // ---- CSR path ----
        hipMemsetAsync(row_ptr, 0, (NN + 1) * sizeof(int), stream);
        init_kernel<<<grid_n4, tpb, 0, stream>>>(
            (const float4*)user_emb, (const float4*)item_emb,
            (float4*)buf0, (float4*)acc);

        hist_kernel<<<grid_e, tpb, 0, stream>>>(adj_rows, row_ptr);
        scan_local<<<NB, SCAN_B, 0, stream>>>(row_ptr, bsum, NN);
        scan_bsum<<<1, 1024, 0, stream>>>(bsum, NB);
        add_offsets<<<NB, SCAN_B, 0, stream>>>(row_ptr, cursor, bsum);
        scatter_edges<<<grid_e, tpb, 0, stream>>>(adj_rows, adj_cols, adj_vals,
                                                  cursor, scols, svals);

        // hop 1: buf0 -> buf1 (+acc)
        spmm_csr<<<grid_r, tpb, 0, stream>>>(row_ptr, scols, svals,
                                             buf0, buf1, acc, scale);
        // hop 2: buf1 -> buf0 (+acc)
        spmm_csr<<<grid_r, tpb, 0, stream>>>(row_ptr, scols, svals,
                                             buf1, buf0, acc, scale);
        // hop 3: buf0 -> buf1 (+acc)
        spmm_csr<<<grid_r, tpb, 0, stream>>>(row_ptr, scols, svals,
                                             buf0, buf1, acc, scale);
    } else {
        // ---- fallback: round-1 atomic scatter path (needs 76.8 MB) ----
        const int grid_e4 = (E_EDGES + 3) / 4;
        init_fb<<<grid_n4, tpb, 0, stream>>>(
            (const float4*)user_emb, (const float4*)item_emb,
            (float4*)buf0, (float4*)buf1, (float4*)acc);
        spmm_scatter<<<grid_e4, tpb, 0, stream>>>(adj_rows, adj_cols, adj_vals, buf0, buf1);
        axpy_zero<<<grid_n4, tpb, 0, stream>>>((const float4*)buf1, (float4*)acc, (float4*)buf0, scale);
        spmm_scatter<<<grid_e4, tpb, 0, stream>>>(adj_rows, adj_cols, adj_vals, buf1, buf0);
        axpy_zero<<<grid_n4, tpb, 0, stream>>>((const float4*)buf0, (float4*)acc, (float4*)buf1, scale);
        spmm_scatter<<<grid_e4, tpb, 0, stream>>>(adj_rows, adj_cols, adj_vals, buf0, buf1);
        axpy_zero<<<grid_n4, tpb, 0, stream>>>((const float4*)buf1, (float4*)acc, (float4*)buf0, scale);
    }
}

// Round 3
// 664.522 us; speedup vs baseline: 2.6107x; 1.2224x over previous
//
#include <hip/hip_runtime.h>

// Problem constants (fixed by reference setup_inputs)
#define N_USERS 100000
#define N_ITEMS 50000
#define NN      (N_USERS + N_ITEMS)   // 150000 nodes
#define DD      64                     // feature dim
#define E_EDGES 2400000
#define HOPS    3
#define SCAN_B  256
#define NB      ((NN + SCAN_B - 1) / SCAN_B)   // 586 scan blocks

// ---------------------------------------------------------------------------
// CSR build step 1: degree histogram into row_ptr[0..NN-1] (pre-zeroed)
// ---------------------------------------------------------------------------
__global__ void hist_kernel(const int* __restrict__ rows, int* __restrict__ deg) {
    int e = blockIdx.x * blockDim.x + threadIdx.x;
    if (e < E_EDGES) atomicAdd(&deg[rows[e]], 1);
}

// ---------------------------------------------------------------------------
// CSR build step 2a: per-block exclusive scan (in-place) + block sums
// ---------------------------------------------------------------------------
__global__ void scan_local(int* __restrict__ data, int* __restrict__ bsum, int n) {
    __shared__ int sh[SCAN_B];
    int i = blockIdx.x * SCAN_B + threadIdx.x;
    int v = (i < n) ? data[i] : 0;
    sh[threadIdx.x] = v;
    __syncthreads();
    for (int off = 1; off < SCAN_B; off <<= 1) {
        int t = (threadIdx.x >= off) ? sh[threadIdx.x - off] : 0;
        __syncthreads();
        sh[threadIdx.x] += t;
        __syncthreads();
    }
    int incl = sh[threadIdx.x];
    if (i < n) data[i] = incl - v;                     // exclusive
    if (threadIdx.x == SCAN_B - 1) bsum[blockIdx.x] = incl;
}

// ---------------------------------------------------------------------------
// CSR build step 2b: single-block exclusive scan of block sums (NB <= 1024)
// ---------------------------------------------------------------------------
__global__ void scan_bsum(int* __restrict__ bsum, int nb) {
    __shared__ int sh[1024];
    int v = ((int)threadIdx.x < nb) ? bsum[threadIdx.x] : 0;
    sh[threadIdx.x] = v;
    __syncthreads();
    for (int off = 1; off < 1024; off <<= 1) {
        int t = ((int)threadIdx.x >= off) ? sh[threadIdx.x - off] : 0;
        __syncthreads();
        sh[threadIdx.x] += t;
        __syncthreads();
    }
    if ((int)threadIdx.x < nb) bsum[threadIdx.x] = sh[threadIdx.x] - v;
}

// ---------------------------------------------------------------------------
// CSR build step 2c: add block offsets; init cursor = row_ptr; set sentinel
// ---------------------------------------------------------------------------
__global__ void add_offsets(int* __restrict__ row_ptr, int* __restrict__ cursor,
                            const int* __restrict__ bsum) {
    int i = blockIdx.x * SCAN_B + threadIdx.x;
    if (i < NN) {
        int v = row_ptr[i] + bsum[blockIdx.x];
        row_ptr[i] = v;
        cursor[i]  = v;
    }
    if (i == 0) row_ptr[NN] = E_EDGES;
}

// ---------------------------------------------------------------------------
// CSR build step 3: scatter packed (col,val) as ONE int2 8B store per edge
// (round-2 post-mortem: two separate 4B stores touched 2 lines/edge ->
//  227 MB write traffic for 19.2 MB payload)
// ---------------------------------------------------------------------------
__global__ void scatter_edges(const int* __restrict__ rows,
                              const int* __restrict__ cols,
                              const float* __restrict__ vals,
                              int* __restrict__ cursor,
                              int2* __restrict__ ep) {
    int e = blockIdx.x * blockDim.x + threadIdx.x;
    if (e >= E_EDGES) return;
    int r = rows[e];
    int pos = atomicAdd(&cursor[r], 1);
    ep[pos] = make_int2(cols[e], __float_as_int(vals[e]));
}

// ---------------------------------------------------------------------------
// CSR SpMM, atomic-free: one wave per row (4 rows / 256-thread block),
// lane = feature column. Row index forced wave-uniform (readfirstlane) so
// row_ptr / edge loads scalarize to s_load, freeing the VMEM pipe for the
// x-gathers; unroll x4 keeps 4 independent 256B gathers in flight.
//   FIRST:   acc = sum*scale (store; covers d_out poison) else acc += ...
//   WRITE_Y: write hop output (skipped on last hop)
//   SPLIT:   hop-1 gathers directly from user/item (wave-uniform s_cselect)
// ---------------------------------------------------------------------------
__device__ __forceinline__ float gather_x(int c, int lane,
                                          const float* __restrict__ xa,
                                          const float* __restrict__ xb,
                                          bool split) {
    if (split) {
        const float* b = (c < N_USERS) ? xa : xb;
        int cc = (c < N_USERS) ? c : c - N_USERS;
        return b[(size_t)cc * DD + lane];
    }
    return xa[(size_t)c * DD + lane];
}

template <bool FIRST, bool WRITE_Y, bool SPLIT>
__global__ void spmm_csr(const int* __restrict__ row_ptr,
                         const int2* __restrict__ ep,
                         const float* __restrict__ xa,
                         const float* __restrict__ xb,
                         float* __restrict__ y,
                         float* __restrict__ acc,
                         float scale) {
    int r = blockIdx.x * 4 + (threadIdx.x >> 6);
    if (r >= NN) return;
    r = __builtin_amdgcn_readfirstlane(r);   // wave-uniform -> SGPR
    int lane = threadIdx.x & 63;
    int s    = row_ptr[r];
    int eend = row_ptr[r + 1];
    float sum = 0.f;
    int e = s;
    for (; e + 3 < eend; e += 4) {
        int2 p0 = ep[e];
        int2 p1 = ep[e + 1];
        int2 p2 = ep[e + 2];
        int2 p3 = ep[e + 3];
        float g0 = gather_x(p0.x, lane, xa, xb, SPLIT);
        float g1 = gather_x(p1.x, lane, xa, xb, SPLIT);
        float g2 = gather_x(p2.x, lane, xa, xb, SPLIT);
        float g3 = gather_x(p3.x, lane, xa, xb, SPLIT);
        sum += __int_as_float(p0.y) * g0;
        sum += __int_as_float(p1.y) * g1;
        sum += __int_as_float(p2.y) * g2;
        sum += __int_as_float(p3.y) * g3;
    }
    for (; e < eend; ++e) {
        int2 p = ep[e];
        sum += __int_as_float(p.y) * gather_x(p.x, lane, xa, xb, SPLIT);
    }
    int o = r * DD + lane;
    if (WRITE_Y) y[o] = sum;
    if (FIRST) acc[o] = sum * scale;
    else       acc[o] += sum * scale;
}

extern "C" void kernel_launch(void* const* d_in, const int* in_sizes, int n_in,
                              void* d_out, int out_size, void* d_ws, size_t ws_size,
                              hipStream_t stream) {
    const float* user_emb = (const float*)d_in[0];
    const float* item_emb = (const float*)d_in[1];
    const int*   adj_rows = (const int*)d_in[2];
    const int*   adj_cols = (const int*)d_in[3];
    const float* adj_vals = (const float*)d_in[4];
    // d_in[5] = hops (always 3 per setup_inputs) -- unrolled host-side.

    float* acc = (float*)d_out;

    // Workspace layout (~97.2 MB; round-2 confirmed ws_size covers this):
    //   buf0, buf1 : NN*DD floats each (hop ping-pong)
    //   ep         : E int2 packed (col,val), 8B-aligned (bufs are 76.8MB)
    //   row_ptr    : NN+1, cursor: NN, bsum: 1024
    float* buf0    = (float*)d_ws;
    float* buf1    = buf0 + (size_t)NN * DD;
    int2*  ep      = (int2*)(buf1 + (size_t)NN * DD);
    int*   row_ptr = (int*)(ep + E_EDGES);
    int*   cursor  = row_ptr + NN + 1;
    int*   bsum    = cursor + NN;

    const int tpb = 256;
    const int grid_e = (E_EDGES + tpb - 1) / tpb;      // 9375
    const int grid_r = (NN + 3) / 4;                   // 37500 (4 rows/block)
    const float scale = 1.0f / (float)HOPS;

    // ---- CSR build (every launch; d_ws is re-poisoned) ----
    hipMemsetAsync(row_ptr, 0, (size_t)NN * sizeof(int), stream);
    hist_kernel<<<grid_e, tpb, 0, stream>>>(adj_rows, row_ptr);
    scan_local<<<NB, SCAN_B, 0, stream>>>(row_ptr, bsum, NN);
    scan_bsum<<<1, 1024, 0, stream>>>(bsum, NB);
    add_offsets<<<NB, SCAN_B, 0, stream>>>(row_ptr, cursor, bsum);
    scatter_edges<<<grid_e, tpb, 0, stream>>>(adj_rows, adj_cols, adj_vals,
                                              cursor, ep);

    // ---- 3 hops, fused acc epilogue ----
    // hop 1: gather straight from user/item; acc = sum/3; y -> buf0
    spmm_csr<true, true, true><<<grid_r, tpb, 0, stream>>>(
        row_ptr, ep, user_emb, item_emb, buf0, acc, scale);
    // hop 2: buf0 -> buf1; acc += sum/3
    spmm_csr<false, true, false><<<grid_r, tpb, 0, stream>>>(
        row_ptr, ep, buf0, nullptr, buf1, acc, scale);
    // hop 3: buf1 -> (no y); acc += sum/3
    spmm_csr<false, false, false><<<grid_r, tpb, 0, stream>>>(
        row_ptr, ep, buf1, nullptr, nullptr, acc, scale);
}